// Round 1
// baseline (111.616 us; speedup 1.0000x reference)
//
#include <hip/hip_runtime.h>
#include <math.h>

// Problem constants (from reference): M=100000 nodes, D=64, G=1024 graphs.
// out[g] = upper-tri of sum_{m in seg g} a_m * x_m x_m^T, a = segment softmax(x.w+b).
// batch is SORTED -> segments are contiguous index ranges.

#define DDIM 64
#define NTRI 2080          // 64*65/2
#define CAP  2048          // LDS cache for per-node imp/exp values (segments are ~98 nodes)
#define TILE 8             // nodes per LDS staging tile in the outer-product sweep

__device__ __forceinline__ float dot_row_w(const float* __restrict__ row,
                                           const float* __restrict__ sW) {
    float d = 0.f;
#pragma unroll
    for (int k = 0; k < 16; ++k) {
        const float4 v = ((const float4*)row)[k];
        const float4 w = ((const float4*)sW)[k];
        d = fmaf(v.x, w.x, d);
        d = fmaf(v.y, w.y, d);
        d = fmaf(v.z, w.z, d);
        d = fmaf(v.w, w.w, d);
    }
    return d;
}

__global__ void __launch_bounds__(256)
attention_sop_kernel(const float* __restrict__ x,
                     const float* __restrict__ att_w,
                     const float* __restrict__ att_b,
                     const int*   __restrict__ batch,
                     float*       __restrict__ out,
                     int M)
{
    const int g   = blockIdx.x;
    const int tid = threadIdx.x;

    __shared__ float sW[DDIM];
    __shared__ float sB;
    __shared__ float sImp[CAP];
    __shared__ float sRed[8];
    __shared__ float sXr[TILE * DDIM];   // raw x tile
    __shared__ float sYs[TILE * DDIM];   // a_m-scaled x tile
    __shared__ int   sBounds[2];

    // --- segment bounds via binary search in sorted batch ---
    if (tid == 0) {
        int lo = 0, hi = M;
        while (lo < hi) { int mid = (lo + hi) >> 1; if (batch[mid] < g) lo = mid + 1; else hi = mid; }
        sBounds[0] = lo;
        int lo2 = lo, hi2 = M;
        while (lo2 < hi2) { int mid = (lo2 + hi2) >> 1; if (batch[mid] < g + 1) lo2 = mid + 1; else hi2 = mid; }
        sBounds[1] = lo2;
    }
    if (tid < DDIM) sW[tid] = att_w[tid];
    if (tid == DDIM) sB = att_b[0];
    __syncthreads();

    const int s = sBounds[0];
    const int e = sBounds[1];
    const int n = e - s;
    const float bb = sB;

    float* og = out + (size_t)g * NTRI;

    if (n == 0) {
        // output is poisoned each run -> must write zeros
        for (int idx = tid; idx < NTRI; idx += 256) og[idx] = 0.f;
        return;
    }

    // --- sweep 1: imp = x.w + b, block max ---
    float lmax = -INFINITY;
    for (int idx = tid; idx < n; idx += 256) {
        const float* row = x + (size_t)(s + idx) * DDIM;
        float d = dot_row_w(row, sW) + bb;
        if (idx < CAP) sImp[idx] = d;
        lmax = fmaxf(lmax, d);
    }
#pragma unroll
    for (int off = 32; off > 0; off >>= 1)
        lmax = fmaxf(lmax, __shfl_down(lmax, off, 64));
    const int wid = tid >> 6, lane = tid & 63;
    if (lane == 0) sRed[wid] = lmax;
    __syncthreads();
    if (tid == 0) {
        float mx = fmaxf(fmaxf(sRed[0], sRed[1]), fmaxf(sRed[2], sRed[3]));
        sRed[4] = mx;
    }
    __syncthreads();
    const float mx = sRed[4];

    // --- sweep 2: e = exp(imp - mx), block sum ---
    float lsum = 0.f;
    for (int idx = tid; idx < n; idx += 256) {
        float d;
        if (idx < CAP) d = sImp[idx];
        else           d = dot_row_w(x + (size_t)(s + idx) * DDIM, sW) + bb;
        float ev = __expf(d - mx);
        if (idx < CAP) sImp[idx] = ev;
        lsum += ev;
    }
#pragma unroll
    for (int off = 32; off > 0; off >>= 1)
        lsum += __shfl_down(lsum, off, 64);
    if (lane == 0) sRed[wid] = lsum;
    __syncthreads();
    if (tid == 0) {
        float denom = sRed[0] + sRed[1] + sRed[2] + sRed[3];
        sRed[5] = 1.0f / denom;
    }
    __syncthreads();
    const float inv = sRed[5];

    // --- sweep 3: acc(i,j) += (a_m * x_i) * x_j, 4x4 register tile per thread ---
    const int ty = tid >> 4, tx = tid & 15;
    const int i0 = ty * 4, j0 = tx * 4;
    float acc[4][4];
#pragma unroll
    for (int a = 0; a < 4; ++a)
#pragma unroll
        for (int b = 0; b < 4; ++b) acc[a][b] = 0.f;

    for (int t0 = 0; t0 < n; t0 += TILE) {
        const int nt = min(TILE, n - t0);
        __syncthreads();   // protect previous tile's LDS reads
        for (int idx = tid; idx < nt * DDIM; idx += 256) {
            const int nn   = idx >> 6;
            const int gidx = t0 + nn;
            float c;
            if (gidx < CAP) {
                c = sImp[gidx] * inv;
            } else {
                float d  = dot_row_w(x + (size_t)(s + gidx) * DDIM, sW) + bb;
                c = __expf(d - mx) * inv;
            }
            const float v = x[(size_t)(s + t0) * DDIM + idx];  // contiguous, coalesced
            sXr[idx] = v;
            sYs[idx] = v * c;
        }
        __syncthreads();
        for (int nn = 0; nn < nt; ++nn) {
            const float4 yi = *(const float4*)&sYs[nn * DDIM + i0];
            const float4 xj = *(const float4*)&sXr[nn * DDIM + j0];
            const float yv[4] = {yi.x, yi.y, yi.z, yi.w};
            const float xv[4] = {xj.x, xj.y, xj.z, xj.w};
#pragma unroll
            for (int a = 0; a < 4; ++a)
#pragma unroll
                for (int b = 0; b < 4; ++b)
                    acc[a][b] = fmaf(yv[a], xv[b], acc[a][b]);
        }
    }

    // --- epilogue: scatter upper triangle (row-major triu incl. diagonal) ---
#pragma unroll
    for (int a = 0; a < 4; ++a) {
        const int i = i0 + a;
        const int base = i * DDIM - (i * (i - 1)) / 2;  // start of row i in triu vec
#pragma unroll
        for (int b = 0; b < 4; ++b) {
            const int j = j0 + b;
            if (j >= i) og[base + (j - i)] = acc[a][b];
        }
    }
}

extern "C" void kernel_launch(void* const* d_in, const int* in_sizes, int n_in,
                              void* d_out, int out_size, void* d_ws, size_t ws_size,
                              hipStream_t stream) {
    const float* x     = (const float*)d_in[0];
    const float* att_w = (const float*)d_in[1];
    const float* att_b = (const float*)d_in[2];
    const int*   batch = (const int*)d_in[3];
    // d_in[4] = edge: dead code in reference
    float* out = (float*)d_out;

    const int M = in_sizes[0] / DDIM;
    const int G = out_size / NTRI;

    attention_sop_kernel<<<G, 256, 0, stream>>>(x, att_w, att_b, batch, out, M);
}

// Round 2
// 102.702 us; speedup vs baseline: 1.0868x; 1.0868x over previous
//
#include <hip/hip_runtime.h>
#include <math.h>

// M=100000 nodes, D=64, G=1024 graphs. batch sorted -> contiguous segments.
// out[g] = triu( sum_{m in seg g} a_m * x_m x_m^T ),  a = segment-softmax(x.w+b)

#define DDIM 64
#define NTRI 2080          // 64*65/2
#define CAP  1024          // LDS cache of exp(imp-mx) per graph (n ~ 98 +- 10)
#define TILE 32            // nodes per staged tile

// ---------------- Kernel A: imp[m] = x[m].w + b ; seg_start[] from sorted batch
__global__ void __launch_bounds__(256)
prep_kernel(const float* __restrict__ x,
            const float* __restrict__ att_w,
            const float* __restrict__ att_b,
            const int*   __restrict__ batch,
            float*       __restrict__ imp,
            int*         __restrict__ seg_start,
            int M, int G)
{
    const int tid    = threadIdx.x;
    const int lane16 = tid & 15;
    const int node   = blockIdx.x * 16 + (tid >> 4);

    if (node < M) {
        const float4 v = ((const float4*)x)[node * 16 + lane16];     // coalesced 16B/lane
        const float4 w = ((const float4*)att_w)[lane16];
        float d = fmaf(v.x, w.x, fmaf(v.y, w.y, fmaf(v.z, w.z, v.w * w.w)));
        d += __shfl_down(d, 8, 16);
        d += __shfl_down(d, 4, 16);
        d += __shfl_down(d, 2, 16);
        d += __shfl_down(d, 1, 16);
        if (lane16 == 0) imp[node] = d + att_b[0];
    }
    // segment boundaries: one thread per node
    if (tid < 16) {
        const int m = blockIdx.x * 16 + tid;
        if (m < M) {
            const int b0 = batch[m];
            if (m == 0) {
                for (int g = 0; g <= b0; ++g) seg_start[g] = 0;
            } else {
                const int bp = batch[m - 1];
                for (int g = bp + 1; g <= b0; ++g) seg_start[g] = m;
            }
            if (m == M - 1) {
                for (int g = b0 + 1; g <= G; ++g) seg_start[g] = M;
            }
        }
    }
}

// ---------------- Kernel C: per-graph softmax (from imp) + sum a_m x x^T
__global__ void __launch_bounds__(256)
sop_kernel(const float* __restrict__ x,
           const float* __restrict__ imp,
           const int*   __restrict__ seg_start,
           float*       __restrict__ out,
           int M)
{
    const int g   = blockIdx.x;
    const int tid = threadIdx.x;

    __shared__ float sA[CAP];            // exp(imp - mx), unscaled
    __shared__ float sX[2][TILE * DDIM]; // double-buffered x tiles
    __shared__ float sAt[2][TILE];       // per-tile a values (scaled)
    __shared__ float sRed[8];

    const int s = seg_start[g];
    const int e = seg_start[g + 1];
    const int n = e - s;
    float* og = out + (size_t)g * NTRI;

    if (n == 0) {                        // out is poisoned -> must write zeros
        for (int i = tid; i < NTRI; i += 256) og[i] = 0.f;
        return;
    }

    // --- softmax stats over imp[s..e) ---
    float lmax = -INFINITY;
    for (int i = tid; i < n; i += 256) lmax = fmaxf(lmax, imp[s + i]);
#pragma unroll
    for (int off = 32; off > 0; off >>= 1) lmax = fmaxf(lmax, __shfl_down(lmax, off, 64));
    const int wid = tid >> 6, lane = tid & 63;
    if (lane == 0) sRed[wid] = lmax;
    __syncthreads();
    if (tid == 0) sRed[4] = fmaxf(fmaxf(sRed[0], sRed[1]), fmaxf(sRed[2], sRed[3]));
    __syncthreads();
    const float mx = sRed[4];

    float lsum = 0.f;
    for (int i = tid; i < n; i += 256) {
        const float ev = __expf(imp[s + i] - mx);
        if (i < CAP) sA[i] = ev;
        lsum += ev;
    }
#pragma unroll
    for (int off = 32; off > 0; off >>= 1) lsum += __shfl_down(lsum, off, 64);
    if (lane == 0) sRed[wid] = lsum;
    __syncthreads();
    if (tid == 0) sRed[5] = 1.0f / (sRed[0] + sRed[1] + sRed[2] + sRed[3]);
    __syncthreads();
    const float inv = sRed[5];

    // --- main loop: acc(i,j) += (a_m x_i) x_j, 4x4 reg tile, double-buffered ---
    const int ty = tid >> 4, tx = tid & 15;
    const int i0 = ty * 4, j0 = tx * 4;
    float acc[4][4];
#pragma unroll
    for (int a = 0; a < 4; ++a)
#pragma unroll
        for (int b = 0; b < 4; ++b) acc[a][b] = 0.f;

    const float4* x4 = (const float4*)x;          // row r = 16 float4s at r*16
    const int T = (n + TILE - 1) / TILE;

    float4 r0, r1;
    {
        const int nt0 = min(TILE, n);
        const long base = (long)s * 16;
        const float4 z = {0.f, 0.f, 0.f, 0.f};
        r0 = (tid       < nt0 * 16) ? x4[base + tid]       : z;
        r1 = (tid + 256 < nt0 * 16) ? x4[base + tid + 256] : z;
    }

    for (int t = 0; t < T; ++t) {
        const int t0  = t * TILE;
        const int nt  = min(TILE, n - t0);
        const int cur = t & 1;

        ((float4*)sX[cur])[tid]       = r0;
        ((float4*)sX[cur])[tid + 256] = r1;
        if (tid < TILE) {
            const int gidx = t0 + tid;
            float av = 0.f;
            if (gidx < n)
                av = ((gidx < CAP) ? sA[gidx] : __expf(imp[s + gidx] - mx)) * inv;
            sAt[cur][tid] = av;
        }
        if (t + 1 < T) {                 // prefetch next tile into registers
            const int t0n = t0 + TILE;
            const int ntn = min(TILE, n - t0n);
            const long base = (long)(s + t0n) * 16;
            const float4 z = {0.f, 0.f, 0.f, 0.f};
            r0 = (tid       < ntn * 16) ? x4[base + tid]       : z;
            r1 = (tid + 256 < ntn * 16) ? x4[base + tid + 256] : z;
        }
        __syncthreads();                 // single barrier per tile (double buffer)

        const float* xb = sX[cur];
        const float* ab = sAt[cur];
        if (nt == TILE) {
#pragma unroll 8
            for (int nn = 0; nn < TILE; ++nn) {
                const float c  = ab[nn];
                const float4 xi = *(const float4*)&xb[nn * DDIM + i0];
                const float4 xj = *(const float4*)&xb[nn * DDIM + j0];
                const float yv[4] = {c * xi.x, c * xi.y, c * xi.z, c * xi.w};
                const float xv[4] = {xj.x, xj.y, xj.z, xj.w};
#pragma unroll
                for (int a = 0; a < 4; ++a)
#pragma unroll
                    for (int b = 0; b < 4; ++b)
                        acc[a][b] = fmaf(yv[a], xv[b], acc[a][b]);
            }
        } else {
            for (int nn = 0; nn < nt; ++nn) {
                const float c  = ab[nn];
                const float4 xi = *(const float4*)&xb[nn * DDIM + i0];
                const float4 xj = *(const float4*)&xb[nn * DDIM + j0];
                const float yv[4] = {c * xi.x, c * xi.y, c * xi.z, c * xi.w};
                const float xv[4] = {xj.x, xj.y, xj.z, xj.w};
#pragma unroll
                for (int a = 0; a < 4; ++a)
#pragma unroll
                    for (int b = 0; b < 4; ++b)
                        acc[a][b] = fmaf(yv[a], xv[b], acc[a][b]);
            }
        }
    }

    // --- epilogue: scatter upper triangle (row-major triu incl. diagonal) ---
#pragma unroll
    for (int a = 0; a < 4; ++a) {
        const int i = i0 + a;
        const int base = i * DDIM - (i * (i - 1)) / 2;
#pragma unroll
        for (int b = 0; b < 4; ++b) {
            const int j = j0 + b;
            if (j >= i) og[base + (j - i)] = acc[a][b];
        }
    }
}

extern "C" void kernel_launch(void* const* d_in, const int* in_sizes, int n_in,
                              void* d_out, int out_size, void* d_ws, size_t ws_size,
                              hipStream_t stream) {
    const float* x     = (const float*)d_in[0];
    const float* att_w = (const float*)d_in[1];
    const float* att_b = (const float*)d_in[2];
    const int*   batch = (const int*)d_in[3];
    // d_in[4] = edge: dead code in reference
    float* out = (float*)d_out;

    const int M = in_sizes[0] / DDIM;
    const int G = out_size / NTRI;

    int*   seg_start = (int*)d_ws;                         // (G+1) ints
    float* imp       = (float*)((char*)d_ws + 8192);       // M floats

    const int blocksA = (M + 15) / 16;
    prep_kernel<<<blocksA, 256, 0, stream>>>(x, att_w, att_b, batch, imp, seg_start, M, G);
    sop_kernel<<<G, 256, 0, stream>>>(x, imp, seg_start, out, M);
}